// Round 4
// baseline (404.366 us; speedup 1.0000x reference)
//
#include <hip/hip_runtime.h>

constexpr int D    = 128;   // node embedding dim
constexpr int K2   = 256;   // 2*D, layer-1 K
constexpr int H    = 256;   // hidden
constexpr int CLS  = 32;    // classes
constexpr int MT   = 64;    // edges per tile
constexpr int LSTR = 264;   // (fallback v1 only) padded LDS stride in ushort

typedef __attribute__((ext_vector_type(8))) __bf16 bf16x8;
typedef __attribute__((ext_vector_type(8))) unsigned short ushort8;
typedef __attribute__((ext_vector_type(4))) float f32x4;

static __device__ __forceinline__ unsigned short f2b(float f) {
  unsigned int u = __float_as_uint(f);
  u += 0x7FFFu + ((u >> 16) & 1u);   // RNE
  return (unsigned short)(u >> 16);
}

static __device__ __forceinline__ void gld_lds16(const unsigned short* gp, unsigned short* lp) {
  __builtin_amdgcn_global_load_lds(
      (const __attribute__((address_space(1))) void*)gp,
      (__attribute__((address_space(3))) void*)lp, 16, 0, 0);
}

// ---------------- prep: weights + table + flag --------------------------------
__global__ void prep_weights(const float* __restrict__ W1, const float* __restrict__ W2,
                             const void* __restrict__ eidx,
                             unsigned short* __restrict__ W1b, unsigned short* __restrict__ W2b,
                             int* __restrict__ flag64) {
  int i = blockIdx.x * 256 + threadIdx.x;
  if (i < H * K2)  W1b[i] = f2b(W1[i]);
  if (i < CLS * H) W2b[i] = f2b(W2[i]);
  if (blockIdx.x == 0 && threadIdx.x == 0) {
    const unsigned int* p = (const unsigned int*)eidx;
    int is64 = 1;
    for (int j = 0; j < 64; ++j) if (p[2 * j + 1] != 0u) { is64 = 0; break; }
    *flag64 = is64;
  }
}

__global__ void prep_table(const float* __restrict__ emb, unsigned short* __restrict__ tab, int n8) {
  int i = blockIdx.x * 256 + threadIdx.x;
  if (i < n8) {
    const float* gp = emb + (size_t)i * 8;
    f32x4 lo = *(const f32x4*)gp, hi = *(const f32x4*)(gp + 4);
    ushort8 v;
    v[0] = f2b(lo[0]); v[1] = f2b(lo[1]); v[2] = f2b(lo[2]); v[3] = f2b(lo[3]);
    v[4] = f2b(hi[0]); v[5] = f2b(hi[1]); v[6] = f2b(hi[2]); v[7] = f2b(hi[3]);
    *(ushort8*)(tab + (size_t)i * 8) = v;
  }
}

// ---------------- counting sort of edges by head node -------------------------
__global__ void k_hist(const void* __restrict__ eidx, const int* __restrict__ flag64,
                       int* __restrict__ bins, int E) {
  int e = blockIdx.x * 256 + threadIdx.x;
  if (e < E) {
    int h = (*flag64) ? (int)((const long long*)eidx)[e] : ((const int*)eidx)[e];
    atomicAdd(&bins[h], 1);
  }
}

__global__ void k_scan1(int* __restrict__ bins, int* __restrict__ bsums, int nbins) {
  __shared__ int lsum[4];
  int t = threadIdx.x;                 // 256 threads, 1024 bins/block
  int idx0 = blockIdx.x * 1024 + t * 4;
  int v[4];
  #pragma unroll
  for (int i = 0; i < 4; ++i) v[i] = (idx0 + i < nbins) ? bins[idx0 + i] : 0;
  int local = v[0] + v[1] + v[2] + v[3];
  int lane = t & 63, w = t >> 6;
  int inc = local;
  #pragma unroll
  for (int off = 1; off < 64; off <<= 1) {
    int n = __shfl_up(inc, off, 64);
    if (lane >= off) inc += n;
  }
  if (lane == 63) lsum[w] = inc;
  __syncthreads();
  int woff = 0;
  #pragma unroll
  for (int i = 0; i < 4; ++i) if (i < w) woff += lsum[i];
  int ex = woff + inc - local;
  #pragma unroll
  for (int i = 0; i < 4; ++i) {
    if (idx0 + i < nbins) bins[idx0 + i] = ex;
    ex += v[i];
  }
  if (t == 255) bsums[blockIdx.x] = woff + inc;
}

// parallel exclusive scan of block sums (nb <= 128 fast path; serial fallback)
__global__ void k_scan2(int* __restrict__ bsums, int nb) {
  if (nb <= 128) {
    __shared__ int ws2[2];
    int t = threadIdx.x;               // 128 threads
    int v = (t < nb) ? bsums[t] : 0;
    int lane = t & 63, w = t >> 6;
    int inc = v;
    #pragma unroll
    for (int off = 1; off < 64; off <<= 1) {
      int n = __shfl_up(inc, off, 64);
      if (lane >= off) inc += n;
    }
    if (lane == 63) ws2[w] = inc;
    __syncthreads();
    int add = (w == 1) ? ws2[0] : 0;
    if (t < nb) bsums[t] = inc - v + add;   // exclusive
  } else if (threadIdx.x == 0) {
    int acc = 0;
    for (int i = 0; i < nb; ++i) { int v = bsums[i]; bsums[i] = acc; acc += v; }
  }
}

__global__ void k_scan3(int* __restrict__ bins, const int* __restrict__ bsums, int nbins) {
  int i = blockIdx.x * 1024 + threadIdx.x * 4;
  int add = bsums[blockIdx.x];
  #pragma unroll
  for (int j = 0; j < 4; ++j)
    if (i + j < nbins) bins[i + j] += add;
}

__global__ void k_scatter(const void* __restrict__ eidx, const int* __restrict__ flag64,
                          int* __restrict__ cursor,
                          int* __restrict__ sh, int* __restrict__ st, int* __restrict__ so, int E) {
  int e = blockIdx.x * 256 + threadIdx.x;
  if (e < E) {
    long long h, tl;
    if (*flag64) { h = ((const long long*)eidx)[e]; tl = ((const long long*)eidx)[E + e]; }
    else         { h = ((const int*)eidx)[e];       tl = ((const int*)eidx)[E + e]; }
    int pos = atomicAdd(&cursor[(int)h], 1);
    sh[pos] = (int)h; st[pos] = (int)tl; so[pos] = e;
  }
}

// ---------------- main fused kernel (v4: sorted edges, nt full-line stores) ---
__global__ __launch_bounds__(256, 2)
void edge_mlp4(const unsigned short* __restrict__ tab,
               const int* __restrict__ sh, const int* __restrict__ st,
               const int* __restrict__ so,
               const unsigned short* __restrict__ W1b, const unsigned short* __restrict__ W2b,
               const float* __restrict__ b1, const float* __restrict__ b2,
               float* __restrict__ out, int E, int ntiles) {
  __shared__ unsigned short Xs[2][MT * 256];   // 2 x 32 KB

  const int tid  = threadIdx.x;
  const int lane = tid & 63;
  const int w    = tid >> 6;
  const int l16  = lane & 15;
  const int q    = lane >> 4;

  bf16x8 afr[4][8];
  #pragma unroll
  for (int a = 0; a < 4; ++a) {
    const unsigned short* rp = W1b + (64 * w + 16 * a + l16) * K2 + q * 8;
    #pragma unroll
    for (int kk = 0; kk < 8; ++kk)
      afr[a][kk] = *(const bf16x8*)(rp + kk * 32);
  }
  f32x4 binit[4];
  #pragma unroll
  for (int a = 0; a < 4; ++a) binit[a] = *(const f32x4*)(b1 + 64 * w + 16 * a + 4 * q);
  f32x4 b2init[2];
  #pragma unroll
  for (int ct = 0; ct < 2; ++ct) b2init[ct] = *(const f32x4*)(b2 + 16 * ct + 4 * q);

  const int G    = lane & 31;        // LDS slot granule within row
  const int half = G >> 4;           // 0 = head node, 1 = tail node
  const int sub  = lane >> 5;        // which of the 2 edges in this instr

  auto stage = [&](int t, unsigned short* Xb) {
    #pragma unroll
    for (int c = 0; c < 8; ++c) {
      int mrow = 16 * w + 2 * c + sub;
      int e = t * MT + mrow; if (e >= E) e = E - 1;
      int id = half ? st[e] : sh[e];
      const unsigned short* gp = tab + (size_t)id * D + ((G ^ mrow) & 15) * 8;
      unsigned short* lp = &Xs[0][0] + (Xb - &Xs[0][0]) + (16 * w + 2 * c) * 256;
      gld_lds16(gp, lp);
    }
  };

  int buf = 0;
  int t0 = blockIdx.x;
  if (t0 < ntiles) stage(t0, &Xs[0][0]);

  for (int t = t0; t < ntiles; t += gridDim.x) {
    __syncthreads();
    unsigned short* Xb = &Xs[buf][0];
    int tn = t + gridDim.x;
    if (tn < ntiles) stage(tn, &Xs[buf ^ 1][0]);

    // ---- layer 1 ----
    f32x4 acc[4][4];
    #pragma unroll
    for (int a = 0; a < 4; ++a)
      #pragma unroll
      for (int tt = 0; tt < 4; ++tt) acc[a][tt] = binit[a];

    #pragma unroll
    for (int tt = 0; tt < 4; ++tt) {
      const unsigned short* rowp = Xb + (16 * tt + l16) * 256;
      #pragma unroll
      for (int kk = 0; kk < 8; ++kk) {
        int slot = (4 * kk + q) ^ l16;
        bf16x8 bfrag = *(const bf16x8*)(rowp + slot * 8);
        #pragma unroll
        for (int a = 0; a < 4; ++a)
          acc[a][tt] = __builtin_amdgcn_mfma_f32_16x16x32_bf16(afr[a][kk], bfrag, acc[a][tt], 0, 0, 0);
      }
    }
    __syncthreads();

    // ---- ReLU + bf16 -> Y in Xb (swizzled) ----
    #pragma unroll
    for (int a = 0; a < 4; ++a) {
      int dg   = 8 * w + 2 * a + (q >> 1);
      int qodd = (q & 1) * 4;
      #pragma unroll
      for (int tt = 0; tt < 4; ++tt) {
        int m = 16 * tt + l16;
        f32x4 v = acc[a][tt];
        unsigned int p0 = (unsigned int)f2b(fmaxf(v[0], 0.f)) | ((unsigned int)f2b(fmaxf(v[1], 0.f)) << 16);
        unsigned int p1 = (unsigned int)f2b(fmaxf(v[2], 0.f)) | ((unsigned int)f2b(fmaxf(v[3], 0.f)) << 16);
        int slot = (dg & 16) | ((dg ^ l16) & 15);
        uint2 pp; pp.x = p0; pp.y = p1;
        *(uint2*)(Xb + m * 256 + slot * 8 + qodd) = pp;
      }
    }
    __syncthreads();

    // ---- layer 2 ----
    f32x4 acc2[2];
    acc2[0] = b2init[0]; acc2[1] = b2init[1];
    const int mrow = 16 * w + l16;
    const unsigned short* yrow = Xb + mrow * 256;
    #pragma unroll
    for (int kk = 0; kk < 8; ++kk) {
      int slot = (4 * kk + q) ^ l16;
      bf16x8 yfrag = *(const bf16x8*)(yrow + slot * 8);
      #pragma unroll
      for (int ct = 0; ct < 2; ++ct) {
        bf16x8 wf = *(const bf16x8*)(W2b + (16 * ct + l16) * H + kk * 32 + q * 8);
        acc2[ct] = __builtin_amdgcn_mfma_f32_16x16x32_bf16(wf, yfrag, acc2[ct], 0, 0, 0);
      }
    }

    // ---- epilogue: LDS transpose (wave-local region = this wave's 16 Y rows,
    // only read by this wave in layer 2) -> full-128B-line nontemporal stores.
    {
      float* regf = (float*)(Xb + (16 * w) * 256);   // 8 KB region, use 2 KB
      // write: lane (l16,q) holds edge l16(local), classes 16ct+4q..+4
      #pragma unroll
      for (int ct = 0; ct < 2; ++ct) {
        int c2 = (4 * ct + q) ^ (l16 & 7);           // XOR-swizzled 16B chunk
        *(f32x4*)(regf + l16 * 32 + c2 * 4) = acc2[ct];
      }
      // read+store: lanes 8k..8k+7 cover one full 128 B output line
      #pragma unroll
      for (int ii = 0; ii < 2; ++ii) {
        int r = (lane >> 3) + 8 * ii;                // local edge 0..15
        int c = lane & 7;                            // 16 B chunk within row
        int c2 = c ^ (r & 7);
        f32x4 val = *(const f32x4*)(regf + r * 32 + c2 * 4);
        int e = t * MT + 16 * w + r;
        if (e < E) {
          int oe = so[e];
          __builtin_nontemporal_store(val, (f32x4*)(out + (size_t)oe * CLS + c * 4));
        }
      }
    }
    buf ^= 1;
  }
}

// ---------------- fallback v2 (unsorted, bf16 table) --------------------------
__global__ __launch_bounds__(256, 2)
void edge_mlp2(const unsigned short* __restrict__ tab, const int* __restrict__ idx32,
               const unsigned short* __restrict__ W1b, const unsigned short* __restrict__ W2b,
               const float* __restrict__ b1, const float* __restrict__ b2,
               float* __restrict__ out, int E, int ntiles) {
  __shared__ unsigned short Xs[2][MT * 256];
  const int tid  = threadIdx.x;
  const int lane = tid & 63;
  const int w    = tid >> 6;
  const int l16  = lane & 15;
  const int q    = lane >> 4;

  bf16x8 afr[4][8];
  #pragma unroll
  for (int a = 0; a < 4; ++a) {
    const unsigned short* rp = W1b + (64 * w + 16 * a + l16) * K2 + q * 8;
    #pragma unroll
    for (int kk = 0; kk < 8; ++kk) afr[a][kk] = *(const bf16x8*)(rp + kk * 32);
  }
  f32x4 binit[4];
  #pragma unroll
  for (int a = 0; a < 4; ++a) binit[a] = *(const f32x4*)(b1 + 64 * w + 16 * a + 4 * q);
  f32x4 b2init[2];
  #pragma unroll
  for (int ct = 0; ct < 2; ++ct) b2init[ct] = *(const f32x4*)(b2 + 16 * ct + 4 * q);

  const int G    = lane & 31;
  const int half = G >> 4;
  const int sub  = lane >> 5;

  auto stage = [&](int t, unsigned short* Xb) {
    #pragma unroll
    for (int c = 0; c < 8; ++c) {
      int mrow = 16 * w + 2 * c + sub;
      int e = t * MT + mrow; if (e >= E) e = E - 1;
      int id = idx32[half ? (E + e) : e];
      const unsigned short* gp = tab + (size_t)id * D + ((G ^ mrow) & 15) * 8;
      unsigned short* lp = &Xs[0][0] + (Xb - &Xs[0][0]) + (16 * w + 2 * c) * 256;
      gld_lds16(gp, lp);
    }
  };

  int buf = 0;
  int t0 = blockIdx.x;
  if (t0 < ntiles) stage(t0, &Xs[0][0]);

  for (int t = t0; t < ntiles; t += gridDim.x) {
    __syncthreads();
    unsigned short* Xb = &Xs[buf][0];
    int tn = t + gridDim.x;
    if (tn < ntiles) stage(tn, &Xs[buf ^ 1][0]);

    f32x4 acc[4][4];
    #pragma unroll
    for (int a = 0; a < 4; ++a)
      #pragma unroll
      for (int tt = 0; tt < 4; ++tt) acc[a][tt] = binit[a];

    #pragma unroll
    for (int tt = 0; tt < 4; ++tt) {
      const unsigned short* rowp = Xb + (16 * tt + l16) * 256;
      #pragma unroll
      for (int kk = 0; kk < 8; ++kk) {
        int slot = (4 * kk + q) ^ l16;
        bf16x8 bfrag = *(const bf16x8*)(rowp + slot * 8);
        #pragma unroll
        for (int a = 0; a < 4; ++a)
          acc[a][tt] = __builtin_amdgcn_mfma_f32_16x16x32_bf16(afr[a][kk], bfrag, acc[a][tt], 0, 0, 0);
      }
    }
    __syncthreads();

    #pragma unroll
    for (int a = 0; a < 4; ++a) {
      int dg   = 8 * w + 2 * a + (q >> 1);
      int qodd = (q & 1) * 4;
      #pragma unroll
      for (int tt = 0; tt < 4; ++tt) {
        int m = 16 * tt + l16;
        f32x4 v = acc[a][tt];
        unsigned int p0 = (unsigned int)f2b(fmaxf(v[0], 0.f)) | ((unsigned int)f2b(fmaxf(v[1], 0.f)) << 16);
        unsigned int p1 = (unsigned int)f2b(fmaxf(v[2], 0.f)) | ((unsigned int)f2b(fmaxf(v[3], 0.f)) << 16);
        int slot = (dg & 16) | ((dg ^ l16) & 15);
        uint2 pp; pp.x = p0; pp.y = p1;
        *(uint2*)(Xb + m * 256 + slot * 8 + qodd) = pp;
      }
    }
    __syncthreads();

    f32x4 acc2[2];
    acc2[0] = b2init[0]; acc2[1] = b2init[1];
    const int mrow = 16 * w + l16;
    const unsigned short* yrow = Xb + mrow * 256;
    #pragma unroll
    for (int kk = 0; kk < 8; ++kk) {
      int slot = (4 * kk + q) ^ l16;
      bf16x8 yfrag = *(const bf16x8*)(yrow + slot * 8);
      #pragma unroll
      for (int ct = 0; ct < 2; ++ct) {
        bf16x8 wf = *(const bf16x8*)(W2b + (16 * ct + l16) * H + kk * 32 + q * 8);
        acc2[ct] = __builtin_amdgcn_mfma_f32_16x16x32_bf16(wf, yfrag, acc2[ct], 0, 0, 0);
      }
    }
    int e = t * MT + mrow;
    if (e < E) {
      #pragma unroll
      for (int ct = 0; ct < 2; ++ct)
        *(f32x4*)(out + (size_t)e * CLS + 16 * ct + 4 * q) = acc2[ct];
    }
    buf ^= 1;
  }
}

__global__ void prep_idx(const void* __restrict__ eidx, int* __restrict__ idx32, int n) {
  __shared__ int sflag;
  if (threadIdx.x == 0) {
    const unsigned int* p = (const unsigned int*)eidx;
    int is64 = 1;
    for (int j = 0; j < 64; ++j) if (p[2 * j + 1] != 0u) { is64 = 0; break; }
    sflag = is64;
  }
  __syncthreads();
  int j = blockIdx.x * 256 + threadIdx.x;
  if (j < n) idx32[j] = sflag ? (int)((const long long*)eidx)[j] : ((const int*)eidx)[j];
}

// ---------------- fallback v1 / naive ----------------------------------------
__global__ __launch_bounds__(256, 2)
void edge_mlp_v1(const float* __restrict__ emb, const void* __restrict__ eidx,
                 const unsigned short* __restrict__ W1b, const unsigned short* __restrict__ W2b,
                 const float* __restrict__ b1, const float* __restrict__ b2,
                 const int* __restrict__ flag64,
                 float* __restrict__ out, int E, int ntiles) {
  __shared__ unsigned short Xsp[MT * LSTR];
  const int tid  = threadIdx.x;
  const int lane = tid & 63;
  const int w    = tid >> 6;
  const int l16  = lane & 15;
  const int q    = lane >> 4;
  const int is64 = *flag64;

  bf16x8 afr[4][8];
  #pragma unroll
  for (int a = 0; a < 4; ++a) {
    const unsigned short* rp = W1b + (64 * w + 16 * a + l16) * K2 + q * 8;
    #pragma unroll
    for (int kk = 0; kk < 8; ++kk) afr[a][kk] = *(const bf16x8*)(rp + kk * 32);
  }
  f32x4 binit[4];
  #pragma unroll
  for (int a = 0; a < 4; ++a) binit[a] = *(const f32x4*)(b1 + 64 * w + 16 * a + 4 * q);
  f32x4 b2init[2];
  #pragma unroll
  for (int ct = 0; ct < 2; ++ct) b2init[ct] = *(const f32x4*)(b2 + 16 * ct + 4 * q);

  for (int t = blockIdx.x; t < ntiles; t += gridDim.x) {
    const int e0 = t * MT;
    #pragma unroll
    for (int c = 0; c < 8; ++c) {
      int chunk = tid + c * 256;
      int m = chunk >> 5, col8 = chunk & 31;
      int e = e0 + m; if (e >= E) e = E - 1;
      int iofs = (col8 < 16) ? e : (E + e);
      long long node = is64 ? ((const long long*)eidx)[iofs] : (long long)(((const int*)eidx)[iofs]);
      const float* gp = emb + (int)node * D + (col8 & 15) * 8;
      f32x4 lo = *(const f32x4*)gp, hi = *(const f32x4*)(gp + 4);
      ushort8 v;
      v[0] = f2b(lo[0]); v[1] = f2b(lo[1]); v[2] = f2b(lo[2]); v[3] = f2b(lo[3]);
      v[4] = f2b(hi[0]); v[5] = f2b(hi[1]); v[6] = f2b(hi[2]); v[7] = f2b(hi[3]);
      *(ushort8*)&Xsp[m * LSTR + col8 * 8] = v;
    }
    __syncthreads();
    f32x4 acc[4][4];
    #pragma unroll
    for (int a = 0; a < 4; ++a)
      #pragma unroll
      for (int tt = 0; tt < 4; ++tt) acc[a][tt] = binit[a];
    #pragma unroll
    for (int tt = 0; tt < 4; ++tt) {
      #pragma unroll
      for (int kk = 0; kk < 8; ++kk) {
        bf16x8 bfrag = *(const bf16x8*)&Xsp[(16 * tt + l16) * LSTR + kk * 32 + q * 8];
        #pragma unroll
        for (int a = 0; a < 4; ++a)
          acc[a][tt] = __builtin_amdgcn_mfma_f32_16x16x32_bf16(afr[a][kk], bfrag, acc[a][tt], 0, 0, 0);
      }
    }
    __syncthreads();
    #pragma unroll
    for (int a = 0; a < 4; ++a) {
      int n0 = 64 * w + 16 * a + 4 * q;
      #pragma unroll
      for (int tt = 0; tt < 4; ++tt) {
        f32x4 v = acc[a][tt];
        unsigned int p0 = (unsigned int)f2b(fmaxf(v[0], 0.f)) | ((unsigned int)f2b(fmaxf(v[1], 0.f)) << 16);
        unsigned int p1 = (unsigned int)f2b(fmaxf(v[2], 0.f)) | ((unsigned int)f2b(fmaxf(v[3], 0.f)) << 16);
        uint2 pp; pp.x = p0; pp.y = p1;
        *(uint2*)&Xsp[(16 * tt + l16) * LSTR + n0] = pp;
      }
    }
    __syncthreads();
    f32x4 acc2[2];
    acc2[0] = b2init[0]; acc2[1] = b2init[1];
    const int mrow = 16 * w + l16;
    #pragma unroll
    for (int kk = 0; kk < 8; ++kk) {
      bf16x8 yfrag = *(const bf16x8*)&Xsp[mrow * LSTR + kk * 32 + q * 8];
      #pragma unroll
      for (int ct = 0; ct < 2; ++ct) {
        bf16x8 wf = *(const bf16x8*)(W2b + (16 * ct + l16) * H + kk * 32 + q * 8);
        acc2[ct] = __builtin_amdgcn_mfma_f32_16x16x32_bf16(wf, yfrag, acc2[ct], 0, 0, 0);
      }
    }
    int e = e0 + mrow;
    if (e < E) {
      #pragma unroll
      for (int ct = 0; ct < 2; ++ct)
        *(f32x4*)(out + (size_t)e * CLS + 16 * ct + 4 * q) = acc2[ct];
    }
    __syncthreads();
  }
}

__global__ void edge_mlp_naive(const float* __restrict__ emb, const void* __restrict__ eidx,
                               const float* __restrict__ W1, const float* __restrict__ b1,
                               const float* __restrict__ W2, const float* __restrict__ b2,
                               float* __restrict__ out, int E) {
  __shared__ float x[K2];
  __shared__ float y[H];
  __shared__ int flag;
  int e = blockIdx.x;
  if (threadIdx.x == 0) {
    const unsigned int* p = (const unsigned int*)eidx;
    int is64 = 1;
    for (int j = 0; j < 16; ++j) if (p[2 * j + 1] != 0u) { is64 = 0; break; }
    flag = is64;
  }
  __syncthreads();
  int tid = threadIdx.x;
  long long s, d;
  if (flag) { s = ((const long long*)eidx)[e]; d = ((const long long*)eidx)[E + e]; }
  else      { s = ((const int*)eidx)[e];       d = ((const int*)eidx)[E + e]; }
  if (tid < D) { x[tid] = emb[(int)s * D + tid]; x[D + tid] = emb[(int)d * D + tid]; }
  __syncthreads();
  float acc = b1[tid];
  const float* wr = W1 + tid * K2;
  for (int k = 0; k < K2; ++k) acc += x[k] * wr[k];
  y[tid] = fmaxf(acc, 0.f);
  __syncthreads();
  if (tid < CLS) {
    float a2 = b2[tid];
    const float* w2 = W2 + tid * H;
    for (int k = 0; k < H; ++k) a2 += y[k] * w2[k];
    out[(size_t)e * CLS + tid] = a2;
  }
}

extern "C" void kernel_launch(void* const* d_in, const int* in_sizes, int n_in,
                              void* d_out, int out_size, void* d_ws, size_t ws_size,
                              hipStream_t stream) {
  const float* emb  = (const float*)d_in[0];
  const void*  eidx = d_in[1];
  const float* W1   = (const float*)d_in[2];
  const float* b1   = (const float*)d_in[3];
  const float* W2   = (const float*)d_in[4];
  const float* b2   = (const float*)d_in[5];
  float* out = (float*)d_out;
  const int nodes_elems = in_sizes[0];        // N_NODES * D
  const int N = nodes_elems / D;              // node count
  const int E = in_sizes[1] / 2;
  const int ntiles = (E + MT - 1) / MT;
  const int nb1 = (N + 1023) / 1024;

  // sorted-path ws layout
  size_t off_tab  = 0;
  size_t off_w1   = (off_tab + (size_t)nodes_elems * 2 + 15) & ~(size_t)15;
  size_t off_w2   = off_w1 + (size_t)H * K2 * 2;
  size_t off_bins = (off_w2 + (size_t)CLS * H * 2 + 15) & ~(size_t)15;
  size_t off_bs   = off_bins + (size_t)N * 4;
  size_t off_sh   = (off_bs + (size_t)nb1 * 4 + 15) & ~(size_t)15;
  size_t off_st   = off_sh + (size_t)E * 4;
  size_t off_so   = off_st + (size_t)E * 4;
  size_t off_flag = off_so + (size_t)E * 4;
  size_t need_sorted = off_flag + 16;

  // v2-path ws layout
  size_t v2_off_idx  = (off_w2 + (size_t)CLS * H * 2 + 15) & ~(size_t)15;
  size_t v2_off_flag = v2_off_idx + (size_t)2 * E * 4;
  size_t need_v2     = v2_off_flag + 16;
  size_t need_weights = (size_t)(H * K2 + CLS * H) * 2 + 64;

  if (ws_size >= need_sorted) {
    unsigned short* tab  = (unsigned short*)((char*)d_ws + off_tab);
    unsigned short* W1b  = (unsigned short*)((char*)d_ws + off_w1);
    unsigned short* W2b  = (unsigned short*)((char*)d_ws + off_w2);
    int* bins = (int*)((char*)d_ws + off_bins);
    int* bs   = (int*)((char*)d_ws + off_bs);
    int* sh   = (int*)((char*)d_ws + off_sh);
    int* st   = (int*)((char*)d_ws + off_st);
    int* so   = (int*)((char*)d_ws + off_so);
    int* flag = (int*)((char*)d_ws + off_flag);

    prep_weights<<<(H * K2 + 255) / 256, 256, 0, stream>>>(W1, W2, eidx, W1b, W2b, flag);
    prep_table<<<(nodes_elems / 8 + 255) / 256, 256, 0, stream>>>(emb, tab, nodes_elems / 8);
    hipMemsetAsync(bins, 0, (size_t)N * 4, stream);
    k_hist<<<(E + 255) / 256, 256, 0, stream>>>(eidx, flag, bins, E);
    k_scan1<<<nb1, 256, 0, stream>>>(bins, bs, N);
    k_scan2<<<1, 128, 0, stream>>>(bs, nb1);
    k_scan3<<<nb1, 256, 0, stream>>>(bins, bs, N);
    k_scatter<<<(E + 255) / 256, 256, 0, stream>>>(eidx, flag, bins, sh, st, so, E);
    edge_mlp4<<<1024, 256, 0, stream>>>(tab, sh, st, so, W1b, W2b, b1, b2, out, E, ntiles);
  } else if (ws_size >= need_v2) {
    unsigned short* tab   = (unsigned short*)((char*)d_ws + off_tab);
    unsigned short* W1b   = (unsigned short*)((char*)d_ws + off_w1);
    unsigned short* W2b   = (unsigned short*)((char*)d_ws + off_w2);
    int*            idx32 = (int*)((char*)d_ws + v2_off_idx);
    int*            flag  = (int*)((char*)d_ws + v2_off_flag);
    prep_weights<<<(H * K2 + 255) / 256, 256, 0, stream>>>(W1, W2, eidx, W1b, W2b, flag);
    prep_table<<<(nodes_elems / 8 + 255) / 256, 256, 0, stream>>>(emb, tab, nodes_elems / 8);
    prep_idx<<<(2 * E + 255) / 256, 256, 0, stream>>>(eidx, idx32, 2 * E);
    edge_mlp2<<<1024, 256, 0, stream>>>(tab, idx32, W1b, W2b, b1, b2, out, E, ntiles);
  } else if (ws_size >= need_weights) {
    unsigned short* W1b = (unsigned short*)d_ws;
    unsigned short* W2b = W1b + H * K2;
    int* flag = (int*)(W2b + CLS * H);
    prep_weights<<<(H * K2 + 255) / 256, 256, 0, stream>>>(W1, W2, eidx, W1b, W2b, flag);
    edge_mlp_v1<<<1024, 256, 0, stream>>>(emb, eidx, W1b, W2b, b1, b2, flag, out, E, ntiles);
  } else {
    edge_mlp_naive<<<E, H, 0, stream>>>(emb, eidx, W1, b1, W2, b2, out, E);
  }
}

// Round 5
// 393.984 us; speedup vs baseline: 1.0264x; 1.0264x over previous
//
#include <hip/hip_runtime.h>

constexpr int D    = 128;   // node embedding dim
constexpr int K2   = 256;   // 2*D, layer-1 K
constexpr int H    = 256;   // hidden
constexpr int CLS  = 32;    // classes
constexpr int MT   = 64;    // edges per tile
constexpr int LSTR = 264;   // (fallback v1 only) padded LDS stride in ushort

typedef __attribute__((ext_vector_type(8))) __bf16 bf16x8;
typedef __attribute__((ext_vector_type(8))) unsigned short ushort8;
typedef __attribute__((ext_vector_type(4))) float f32x4;

static __device__ __forceinline__ unsigned short f2b(float f) {
  unsigned int u = __float_as_uint(f);
  u += 0x7FFFu + ((u >> 16) & 1u);   // RNE
  return (unsigned short)(u >> 16);
}

static __device__ __forceinline__ void gld_lds16(const unsigned short* gp, unsigned short* lp) {
  __builtin_amdgcn_global_load_lds(
      (const __attribute__((address_space(1))) void*)gp,
      (__attribute__((address_space(3))) void*)lp, 16, 0, 0);
}

// ---------------- prep: weights + table + flag --------------------------------
__global__ void prep_weights(const float* __restrict__ W1, const float* __restrict__ W2,
                             const void* __restrict__ eidx,
                             unsigned short* __restrict__ W1b, unsigned short* __restrict__ W2b,
                             int* __restrict__ flag64) {
  int i = blockIdx.x * 256 + threadIdx.x;
  if (i < H * K2)  W1b[i] = f2b(W1[i]);
  if (i < CLS * H) W2b[i] = f2b(W2[i]);
  if (blockIdx.x == 0 && threadIdx.x == 0) {
    const unsigned int* p = (const unsigned int*)eidx;
    int is64 = 1;
    for (int j = 0; j < 64; ++j) if (p[2 * j + 1] != 0u) { is64 = 0; break; }
    *flag64 = is64;
  }
}

__global__ void prep_table(const float* __restrict__ emb, unsigned short* __restrict__ tab, int n8) {
  int i = blockIdx.x * 256 + threadIdx.x;
  if (i < n8) {
    const float* gp = emb + (size_t)i * 8;
    f32x4 lo = *(const f32x4*)gp, hi = *(const f32x4*)(gp + 4);
    ushort8 v;
    v[0] = f2b(lo[0]); v[1] = f2b(lo[1]); v[2] = f2b(lo[2]); v[3] = f2b(lo[3]);
    v[4] = f2b(hi[0]); v[5] = f2b(hi[1]); v[6] = f2b(hi[2]); v[7] = f2b(hi[3]);
    *(ushort8*)(tab + (size_t)i * 8) = v;
  }
}

// ---------------- cheap 8-way bucketing by head slice -------------------------
// cnt layout: cnt[0..7]=bsize, cnt[8..15]=bstart, cnt[16..23]=bcur
__global__ void k_zero8(int* __restrict__ cnt) {
  if (threadIdx.x < 24) cnt[threadIdx.x] = 0;
}

__global__ void k_count8(const void* __restrict__ eidx, const int* __restrict__ flag64,
                         int* __restrict__ cnt, int E, int slice_sz) {
  __shared__ int h[8];
  if (threadIdx.x < 8) h[threadIdx.x] = 0;
  __syncthreads();
  int e = blockIdx.x * 256 + threadIdx.x;
  if (e < E) {
    int hd = (*flag64) ? (int)((const long long*)eidx)[e] : ((const int*)eidx)[e];
    atomicAdd(&h[hd / slice_sz], 1);
  }
  __syncthreads();
  if (threadIdx.x < 8 && h[threadIdx.x] > 0) atomicAdd(&cnt[threadIdx.x], h[threadIdx.x]);
}

__global__ void k_offsets8(int* __restrict__ cnt) {
  if (threadIdx.x == 0) {
    int acc = 0;
    for (int i = 0; i < 8; ++i) { cnt[8 + i] = acc; cnt[16 + i] = acc; acc += cnt[i]; }
  }
}

__global__ void k_bucket(const void* __restrict__ eidx, const int* __restrict__ flag64,
                         int* __restrict__ cnt,
                         int* __restrict__ sh, int* __restrict__ st, int* __restrict__ so,
                         int E, int slice_sz) {
  __shared__ int h[8];
  __shared__ int base[8];
  if (threadIdx.x < 8) h[threadIdx.x] = 0;
  __syncthreads();
  int e = blockIdx.x * 256 + threadIdx.x;
  int hd = 0, tl = 0, b = 0, rank = 0;
  if (e < E) {
    if (*flag64) { hd = (int)((const long long*)eidx)[e]; tl = (int)((const long long*)eidx)[E + e]; }
    else         { hd = ((const int*)eidx)[e];            tl = ((const int*)eidx)[E + e]; }
    b = hd / slice_sz;
    rank = atomicAdd(&h[b], 1);
  }
  __syncthreads();
  if (threadIdx.x < 8)
    base[threadIdx.x] = (h[threadIdx.x] > 0) ? atomicAdd(&cnt[16 + threadIdx.x], h[threadIdx.x]) : 0;
  __syncthreads();
  if (e < E) {
    int pos = base[b] + rank;
    sh[pos] = hd; st[pos] = tl; so[pos] = e;
  }
}

// ---------------- main fused kernel (v5: XCD slice partitioning) --------------
// Block b serves head-slice s = b&7 (round-robin blockIdx->XCD heuristic):
// all its head gathers land in one 3.2 MB table slice that stays L2-resident
// on that XCD. Tails remain random (L3-served). Same MFMA core as v2-v4.
__global__ __launch_bounds__(256, 2)
void edge_mlp5(const unsigned short* __restrict__ tab,
               const int* __restrict__ sh, const int* __restrict__ st,
               const int* __restrict__ so, const int* __restrict__ cnt,
               const unsigned short* __restrict__ W1b, const unsigned short* __restrict__ W2b,
               const float* __restrict__ b1, const float* __restrict__ b2,
               float* __restrict__ out) {
  __shared__ unsigned short Xs[2][MT * 256];   // 2 x 32 KB

  const int tid  = threadIdx.x;
  const int lane = tid & 63;
  const int w    = tid >> 6;
  const int l16  = lane & 15;
  const int q    = lane >> 4;

  bf16x8 afr[4][8];
  #pragma unroll
  for (int a = 0; a < 4; ++a) {
    const unsigned short* rp = W1b + (64 * w + 16 * a + l16) * K2 + q * 8;
    #pragma unroll
    for (int kk = 0; kk < 8; ++kk)
      afr[a][kk] = *(const bf16x8*)(rp + kk * 32);
  }
  f32x4 binit[4];
  #pragma unroll
  for (int a = 0; a < 4; ++a) binit[a] = *(const f32x4*)(b1 + 64 * w + 16 * a + 4 * q);
  f32x4 b2init[2];
  #pragma unroll
  for (int ct = 0; ct < 2; ++ct) b2init[ct] = *(const f32x4*)(b2 + 16 * ct + 4 * q);

  const int G    = lane & 31;        // LDS slot granule within row
  const int half = G >> 4;           // 0 = head node, 1 = tail node
  const int sub  = lane >> 5;        // which of the 2 edges in this instr

  const int s     = blockIdx.x & 7;      // slice
  const int j     = blockIdx.x >> 3;     // sub-id within slice
  const int nblk  = gridDim.x >> 3;      // blocks per slice
  const int start = cnt[8 + s];
  const int size  = cnt[s];
  const int lim   = start + size;
  const int nt    = (size + MT - 1) / MT;

  auto stage = [&](int ebase, unsigned short* Xb) {
    #pragma unroll
    for (int c = 0; c < 8; ++c) {
      int mrow = 16 * w + 2 * c + sub;
      int e = ebase + mrow; if (e >= lim) e = lim - 1;
      int id = half ? st[e] : sh[e];
      const unsigned short* gp = tab + (size_t)id * D + ((G ^ mrow) & 15) * 8;
      unsigned short* lp = &Xs[0][0] + (Xb - &Xs[0][0]) + (16 * w + 2 * c) * 256;
      gld_lds16(gp, lp);
    }
  };

  int buf = 0;
  if (j < nt) stage(start + MT * j, &Xs[0][0]);

  for (int tl = j; tl < nt; tl += nblk) {
    __syncthreads();
    unsigned short* Xb = &Xs[buf][0];
    int tn = tl + nblk;
    if (tn < nt) stage(start + MT * tn, &Xs[buf ^ 1][0]);

    // ---- layer 1 ----
    f32x4 acc[4][4];
    #pragma unroll
    for (int a = 0; a < 4; ++a)
      #pragma unroll
      for (int tt = 0; tt < 4; ++tt) acc[a][tt] = binit[a];

    #pragma unroll
    for (int tt = 0; tt < 4; ++tt) {
      const unsigned short* rowp = Xb + (16 * tt + l16) * 256;
      #pragma unroll
      for (int kk = 0; kk < 8; ++kk) {
        int slot = (4 * kk + q) ^ l16;
        bf16x8 bfrag = *(const bf16x8*)(rowp + slot * 8);
        #pragma unroll
        for (int a = 0; a < 4; ++a)
          acc[a][tt] = __builtin_amdgcn_mfma_f32_16x16x32_bf16(afr[a][kk], bfrag, acc[a][tt], 0, 0, 0);
      }
    }
    __syncthreads();

    // ---- ReLU + bf16 -> Y in Xb (swizzled) ----
    #pragma unroll
    for (int a = 0; a < 4; ++a) {
      int dg   = 8 * w + 2 * a + (q >> 1);
      int qodd = (q & 1) * 4;
      #pragma unroll
      for (int tt = 0; tt < 4; ++tt) {
        int m = 16 * tt + l16;
        f32x4 v = acc[a][tt];
        unsigned int p0 = (unsigned int)f2b(fmaxf(v[0], 0.f)) | ((unsigned int)f2b(fmaxf(v[1], 0.f)) << 16);
        unsigned int p1 = (unsigned int)f2b(fmaxf(v[2], 0.f)) | ((unsigned int)f2b(fmaxf(v[3], 0.f)) << 16);
        int slot = (dg & 16) | ((dg ^ l16) & 15);
        uint2 pp; pp.x = p0; pp.y = p1;
        *(uint2*)(Xb + m * 256 + slot * 8 + qodd) = pp;
      }
    }
    __syncthreads();

    // ---- layer 2 ----
    f32x4 acc2[2];
    acc2[0] = b2init[0]; acc2[1] = b2init[1];
    const int mrow = 16 * w + l16;
    const unsigned short* yrow = Xb + mrow * 256;
    #pragma unroll
    for (int kk = 0; kk < 8; ++kk) {
      int slot = (4 * kk + q) ^ l16;
      bf16x8 yfrag = *(const bf16x8*)(yrow + slot * 8);
      #pragma unroll
      for (int ct = 0; ct < 2; ++ct) {
        bf16x8 wf = *(const bf16x8*)(W2b + (16 * ct + l16) * H + kk * 32 + q * 8);
        acc2[ct] = __builtin_amdgcn_mfma_f32_16x16x32_bf16(wf, yfrag, acc2[ct], 0, 0, 0);
      }
    }

    // ---- epilogue: wave-local LDS transpose -> full-128B-line stores ----
    {
      const int ebase = start + MT * tl;
      float* regf = (float*)(Xb + (16 * w) * 256);
      #pragma unroll
      for (int ct = 0; ct < 2; ++ct) {
        int c2 = (4 * ct + q) ^ (l16 & 7);
        *(f32x4*)(regf + l16 * 32 + c2 * 4) = acc2[ct];
      }
      #pragma unroll
      for (int ii = 0; ii < 2; ++ii) {
        int r = (lane >> 3) + 8 * ii;
        int c = lane & 7;
        int c2 = c ^ (r & 7);
        f32x4 val = *(const f32x4*)(regf + r * 32 + c2 * 4);
        int e = ebase + 16 * w + r;
        if (e < lim) {
          int oe = so[e];
          *(f32x4*)(out + (size_t)oe * CLS + c * 4) = val;
        }
      }
    }
    buf ^= 1;
  }
}

// ---------------- fallback v2 (unsorted, bf16 table) --------------------------
__global__ __launch_bounds__(256, 2)
void edge_mlp2(const unsigned short* __restrict__ tab, const int* __restrict__ idx32,
               const unsigned short* __restrict__ W1b, const unsigned short* __restrict__ W2b,
               const float* __restrict__ b1, const float* __restrict__ b2,
               float* __restrict__ out, int E, int ntiles) {
  __shared__ unsigned short Xs[2][MT * 256];
  const int tid  = threadIdx.x;
  const int lane = tid & 63;
  const int w    = tid >> 6;
  const int l16  = lane & 15;
  const int q    = lane >> 4;

  bf16x8 afr[4][8];
  #pragma unroll
  for (int a = 0; a < 4; ++a) {
    const unsigned short* rp = W1b + (64 * w + 16 * a + l16) * K2 + q * 8;
    #pragma unroll
    for (int kk = 0; kk < 8; ++kk) afr[a][kk] = *(const bf16x8*)(rp + kk * 32);
  }
  f32x4 binit[4];
  #pragma unroll
  for (int a = 0; a < 4; ++a) binit[a] = *(const f32x4*)(b1 + 64 * w + 16 * a + 4 * q);
  f32x4 b2init[2];
  #pragma unroll
  for (int ct = 0; ct < 2; ++ct) b2init[ct] = *(const f32x4*)(b2 + 16 * ct + 4 * q);

  const int G    = lane & 31;
  const int half = G >> 4;
  const int sub  = lane >> 5;

  auto stage = [&](int t, unsigned short* Xb) {
    #pragma unroll
    for (int c = 0; c < 8; ++c) {
      int mrow = 16 * w + 2 * c + sub;
      int e = t * MT + mrow; if (e >= E) e = E - 1;
      int id = idx32[half ? (E + e) : e];
      const unsigned short* gp = tab + (size_t)id * D + ((G ^ mrow) & 15) * 8;
      unsigned short* lp = &Xs[0][0] + (Xb - &Xs[0][0]) + (16 * w + 2 * c) * 256;
      gld_lds16(gp, lp);
    }
  };

  int buf = 0;
  int t0 = blockIdx.x;
  if (t0 < ntiles) stage(t0, &Xs[0][0]);

  for (int t = t0; t < ntiles; t += gridDim.x) {
    __syncthreads();
    unsigned short* Xb = &Xs[buf][0];
    int tn = t + gridDim.x;
    if (tn < ntiles) stage(tn, &Xs[buf ^ 1][0]);

    f32x4 acc[4][4];
    #pragma unroll
    for (int a = 0; a < 4; ++a)
      #pragma unroll
      for (int tt = 0; tt < 4; ++tt) acc[a][tt] = binit[a];

    #pragma unroll
    for (int tt = 0; tt < 4; ++tt) {
      const unsigned short* rowp = Xb + (16 * tt + l16) * 256;
      #pragma unroll
      for (int kk = 0; kk < 8; ++kk) {
        int slot = (4 * kk + q) ^ l16;
        bf16x8 bfrag = *(const bf16x8*)(rowp + slot * 8);
        #pragma unroll
        for (int a = 0; a < 4; ++a)
          acc[a][tt] = __builtin_amdgcn_mfma_f32_16x16x32_bf16(afr[a][kk], bfrag, acc[a][tt], 0, 0, 0);
      }
    }
    __syncthreads();

    #pragma unroll
    for (int a = 0; a < 4; ++a) {
      int dg   = 8 * w + 2 * a + (q >> 1);
      int qodd = (q & 1) * 4;
      #pragma unroll
      for (int tt = 0; tt < 4; ++tt) {
        int m = 16 * tt + l16;
        f32x4 v = acc[a][tt];
        unsigned int p0 = (unsigned int)f2b(fmaxf(v[0], 0.f)) | ((unsigned int)f2b(fmaxf(v[1], 0.f)) << 16);
        unsigned int p1 = (unsigned int)f2b(fmaxf(v[2], 0.f)) | ((unsigned int)f2b(fmaxf(v[3], 0.f)) << 16);
        int slot = (dg & 16) | ((dg ^ l16) & 15);
        uint2 pp; pp.x = p0; pp.y = p1;
        *(uint2*)(Xb + m * 256 + slot * 8 + qodd) = pp;
      }
    }
    __syncthreads();

    f32x4 acc2[2];
    acc2[0] = b2init[0]; acc2[1] = b2init[1];
    const int mrow = 16 * w + l16;
    const unsigned short* yrow = Xb + mrow * 256;
    #pragma unroll
    for (int kk = 0; kk < 8; ++kk) {
      int slot = (4 * kk + q) ^ l16;
      bf16x8 yfrag = *(const bf16x8*)(yrow + slot * 8);
      #pragma unroll
      for (int ct = 0; ct < 2; ++ct) {
        bf16x8 wf = *(const bf16x8*)(W2b + (16 * ct + l16) * H + kk * 32 + q * 8);
        acc2[ct] = __builtin_amdgcn_mfma_f32_16x16x32_bf16(wf, yfrag, acc2[ct], 0, 0, 0);
      }
    }
    int e = t * MT + mrow;
    if (e < E) {
      #pragma unroll
      for (int ct = 0; ct < 2; ++ct)
        *(f32x4*)(out + (size_t)e * CLS + 16 * ct + 4 * q) = acc2[ct];
    }
    buf ^= 1;
  }
}

__global__ void prep_idx(const void* __restrict__ eidx, int* __restrict__ idx32, int n) {
  __shared__ int sflag;
  if (threadIdx.x == 0) {
    const unsigned int* p = (const unsigned int*)eidx;
    int is64 = 1;
    for (int j = 0; j < 64; ++j) if (p[2 * j + 1] != 0u) { is64 = 0; break; }
    sflag = is64;
  }
  __syncthreads();
  int j = blockIdx.x * 256 + threadIdx.x;
  if (j < n) idx32[j] = sflag ? (int)((const long long*)eidx)[j] : ((const int*)eidx)[j];
}

// ---------------- fallback v1 / naive ----------------------------------------
__global__ __launch_bounds__(256, 2)
void edge_mlp_v1(const float* __restrict__ emb, const void* __restrict__ eidx,
                 const unsigned short* __restrict__ W1b, const unsigned short* __restrict__ W2b,
                 const float* __restrict__ b1, const float* __restrict__ b2,
                 const int* __restrict__ flag64,
                 float* __restrict__ out, int E, int ntiles) {
  __shared__ unsigned short Xsp[MT * LSTR];
  const int tid  = threadIdx.x;
  const int lane = tid & 63;
  const int w    = tid >> 6;
  const int l16  = lane & 15;
  const int q    = lane >> 4;
  const int is64 = *flag64;

  bf16x8 afr[4][8];
  #pragma unroll
  for (int a = 0; a < 4; ++a) {
    const unsigned short* rp = W1b + (64 * w + 16 * a + l16) * K2 + q * 8;
    #pragma unroll
    for (int kk = 0; kk < 8; ++kk) afr[a][kk] = *(const bf16x8*)(rp + kk * 32);
  }
  f32x4 binit[4];
  #pragma unroll
  for (int a = 0; a < 4; ++a) binit[a] = *(const f32x4*)(b1 + 64 * w + 16 * a + 4 * q);
  f32x4 b2init[2];
  #pragma unroll
  for (int ct = 0; ct < 2; ++ct) b2init[ct] = *(const f32x4*)(b2 + 16 * ct + 4 * q);

  for (int t = blockIdx.x; t < ntiles; t += gridDim.x) {
    const int e0 = t * MT;
    #pragma unroll
    for (int c = 0; c < 8; ++c) {
      int chunk = tid + c * 256;
      int m = chunk >> 5, col8 = chunk & 31;
      int e = e0 + m; if (e >= E) e = E - 1;
      int iofs = (col8 < 16) ? e : (E + e);
      long long node = is64 ? ((const long long*)eidx)[iofs] : (long long)(((const int*)eidx)[iofs]);
      const float* gp = emb + (int)node * D + (col8 & 15) * 8;
      f32x4 lo = *(const f32x4*)gp, hi = *(const f32x4*)(gp + 4);
      ushort8 v;
      v[0] = f2b(lo[0]); v[1] = f2b(lo[1]); v[2] = f2b(lo[2]); v[3] = f2b(lo[3]);
      v[4] = f2b(hi[0]); v[5] = f2b(hi[1]); v[6] = f2b(hi[2]); v[7] = f2b(hi[3]);
      *(ushort8*)&Xsp[m * LSTR + col8 * 8] = v;
    }
    __syncthreads();
    f32x4 acc[4][4];
    #pragma unroll
    for (int a = 0; a < 4; ++a)
      #pragma unroll
      for (int tt = 0; tt < 4; ++tt) acc[a][tt] = binit[a];
    #pragma unroll
    for (int tt = 0; tt < 4; ++tt) {
      #pragma unroll
      for (int kk = 0; kk < 8; ++kk) {
        bf16x8 bfrag = *(const bf16x8*)&Xsp[(16 * tt + l16) * LSTR + kk * 32 + q * 8];
        #pragma unroll
        for (int a = 0; a < 4; ++a)
          acc[a][tt] = __builtin_amdgcn_mfma_f32_16x16x32_bf16(afr[a][kk], bfrag, acc[a][tt], 0, 0, 0);
      }
    }
    __syncthreads();
    #pragma unroll
    for (int a = 0; a < 4; ++a) {
      int n0 = 64 * w + 16 * a + 4 * q;
      #pragma unroll
      for (int tt = 0; tt < 4; ++tt) {
        f32x4 v = acc[a][tt];
        unsigned int p0 = (unsigned int)f2b(fmaxf(v[0], 0.f)) | ((unsigned int)f2b(fmaxf(v[1], 0.f)) << 16);
        unsigned int p1 = (unsigned int)f2b(fmaxf(v[2], 0.f)) | ((unsigned int)f2b(fmaxf(v[3], 0.f)) << 16);
        uint2 pp; pp.x = p0; pp.y = p1;
        *(uint2*)&Xsp[(16 * tt + l16) * LSTR + n0] = pp;
      }
    }
    __syncthreads();
    f32x4 acc2[2];
    acc2[0] = b2init[0]; acc2[1] = b2init[1];
    const int mrow = 16 * w + l16;
    #pragma unroll
    for (int kk = 0; kk < 8; ++kk) {
      bf16x8 yfrag = *(const bf16x8*)&Xsp[mrow * LSTR + kk * 32 + q * 8];
      #pragma unroll
      for (int ct = 0; ct < 2; ++ct) {
        bf16x8 wf = *(const bf16x8*)(W2b + (16 * ct + l16) * H + kk * 32 + q * 8);
        acc2[ct] = __builtin_amdgcn_mfma_f32_16x16x32_bf16(wf, yfrag, acc2[ct], 0, 0, 0);
      }
    }
    int e = e0 + mrow;
    if (e < E) {
      #pragma unroll
      for (int ct = 0; ct < 2; ++ct)
        *(f32x4*)(out + (size_t)e * CLS + 16 * ct + 4 * q) = acc2[ct];
    }
    __syncthreads();
  }
}

__global__ void edge_mlp_naive(const float* __restrict__ emb, const void* __restrict__ eidx,
                               const float* __restrict__ W1, const float* __restrict__ b1,
                               const float* __restrict__ W2, const float* __restrict__ b2,
                               float* __restrict__ out, int E) {
  __shared__ float x[K2];
  __shared__ float y[H];
  __shared__ int flag;
  int e = blockIdx.x;
  if (threadIdx.x == 0) {
    const unsigned int* p = (const unsigned int*)eidx;
    int is64 = 1;
    for (int j = 0; j < 16; ++j) if (p[2 * j + 1] != 0u) { is64 = 0; break; }
    flag = is64;
  }
  __syncthreads();
  int tid = threadIdx.x;
  long long s, d;
  if (flag) { s = ((const long long*)eidx)[e]; d = ((const long long*)eidx)[E + e]; }
  else      { s = ((const int*)eidx)[e];       d = ((const int*)eidx)[E + e]; }
  if (tid < D) { x[tid] = emb[(int)s * D + tid]; x[D + tid] = emb[(int)d * D + tid]; }
  __syncthreads();
  float acc = b1[tid];
  const float* wr = W1 + tid * K2;
  for (int k = 0; k < K2; ++k) acc += x[k] * wr[k];
  y[tid] = fmaxf(acc, 0.f);
  __syncthreads();
  if (tid < CLS) {
    float a2 = b2[tid];
    const float* w2 = W2 + tid * H;
    for (int k = 0; k < H; ++k) a2 += y[k] * w2[k];
    out[(size_t)e * CLS + tid] = a2;
  }
}

extern "C" void kernel_launch(void* const* d_in, const int* in_sizes, int n_in,
                              void* d_out, int out_size, void* d_ws, size_t ws_size,
                              hipStream_t stream) {
  const float* emb  = (const float*)d_in[0];
  const void*  eidx = d_in[1];
  const float* W1   = (const float*)d_in[2];
  const float* b1   = (const float*)d_in[3];
  const float* W2   = (const float*)d_in[4];
  const float* b2   = (const float*)d_in[5];
  float* out = (float*)d_out;
  const int nodes_elems = in_sizes[0];        // N_NODES * D
  const int N = nodes_elems / D;              // node count
  const int E = in_sizes[1] / 2;
  const int ntiles = (E + MT - 1) / MT;
  const int slice_sz = (N + 7) / 8;

  // bucket-path ws layout: [tab][W1b][W2b][sh][st][so][cnt24][flag]
  size_t off_tab  = 0;
  size_t off_w1   = (off_tab + (size_t)nodes_elems * 2 + 15) & ~(size_t)15;
  size_t off_w2   = off_w1 + (size_t)H * K2 * 2;
  size_t off_sh   = (off_w2 + (size_t)CLS * H * 2 + 15) & ~(size_t)15;
  size_t off_st   = off_sh + (size_t)E * 4;
  size_t off_so   = off_st + (size_t)E * 4;
  size_t off_cnt  = off_so + (size_t)E * 4;
  size_t off_flag = off_cnt + 24 * 4;
  size_t need_bucket = off_flag + 16;

  // v2-path ws layout
  size_t v2_off_idx  = (off_w2 + (size_t)CLS * H * 2 + 15) & ~(size_t)15;
  size_t v2_off_flag = v2_off_idx + (size_t)2 * E * 4;
  size_t need_v2     = v2_off_flag + 16;
  size_t need_weights = (size_t)(H * K2 + CLS * H) * 2 + 64;

  if (ws_size >= need_bucket) {
    unsigned short* tab  = (unsigned short*)((char*)d_ws + off_tab);
    unsigned short* W1b  = (unsigned short*)((char*)d_ws + off_w1);
    unsigned short* W2b  = (unsigned short*)((char*)d_ws + off_w2);
    int* sh   = (int*)((char*)d_ws + off_sh);
    int* st   = (int*)((char*)d_ws + off_st);
    int* so   = (int*)((char*)d_ws + off_so);
    int* cnt  = (int*)((char*)d_ws + off_cnt);
    int* flag = (int*)((char*)d_ws + off_flag);

    prep_weights<<<(H * K2 + 255) / 256, 256, 0, stream>>>(W1, W2, eidx, W1b, W2b, flag);
    prep_table<<<(nodes_elems / 8 + 255) / 256, 256, 0, stream>>>(emb, tab, nodes_elems / 8);
    k_zero8<<<1, 64, 0, stream>>>(cnt);
    k_count8<<<(E + 255) / 256, 256, 0, stream>>>(eidx, flag, cnt, E, slice_sz);
    k_offsets8<<<1, 64, 0, stream>>>(cnt);
    k_bucket<<<(E + 255) / 256, 256, 0, stream>>>(eidx, flag, cnt, sh, st, so, E, slice_sz);
    edge_mlp5<<<1024, 256, 0, stream>>>(tab, sh, st, so, cnt, W1b, W2b, b1, b2, out);
  } else if (ws_size >= need_v2) {
    unsigned short* tab   = (unsigned short*)((char*)d_ws + off_tab);
    unsigned short* W1b   = (unsigned short*)((char*)d_ws + off_w1);
    unsigned short* W2b   = (unsigned short*)((char*)d_ws + off_w2);
    int*            idx32 = (int*)((char*)d_ws + v2_off_idx);
    int*            flag  = (int*)((char*)d_ws + v2_off_flag);
    prep_weights<<<(H * K2 + 255) / 256, 256, 0, stream>>>(W1, W2, eidx, W1b, W2b, flag);
    prep_table<<<(nodes_elems / 8 + 255) / 256, 256, 0, stream>>>(emb, tab, nodes_elems / 8);
    prep_idx<<<(2 * E + 255) / 256, 256, 0, stream>>>(eidx, idx32, 2 * E);
    edge_mlp2<<<1024, 256, 0, stream>>>(tab, idx32, W1b, W2b, b1, b2, out, E, ntiles);
  } else if (ws_size >= need_weights) {
    unsigned short* W1b = (unsigned short*)d_ws;
    unsigned short* W2b = W1b + H * K2;
    int* flag = (int*)(W2b + CLS * H);
    prep_weights<<<(H * K2 + 255) / 256, 256, 0, stream>>>(W1, W2, eidx, W1b, W2b, flag);
    edge_mlp_v1<<<1024, 256, 0, stream>>>(emb, eidx, W1b, W2b, b1, b2, flag, out, E, ntiles);
  } else {
    edge_mlp_naive<<<E, H, 0, stream>>>(emb, eidx, W1, b1, W2, b2, out, E);
  }
}